// Round 3
// baseline (719.785 us; speedup 1.0000x reference)
//
#include <hip/hip_runtime.h>
#include <cstddef>
#include <cstdint>

#define BSZ  2
#define SEQ  4096
#define HQN  32
#define HKVN 2
#define DIM  128
#define NBK  255
#define NBP  256
#define GRP  16

typedef __attribute__((ext_vector_type(8))) short bf16x8;
typedef __attribute__((ext_vector_type(4))) float f32x4;

#define MFMA16(A,B,C) __builtin_amdgcn_mfma_f32_16x16x32_bf16((A),(B),(C),0,0,0)

// split x into bf16 hi + bf16 lo (RNE both): x ~= hi + lo, |dropped| ~ 2^-18 |x|
__device__ __forceinline__ void cvt8(const float* x, bf16x8& hi, bf16x8& lo)
{
  #pragma unroll
  for (int i = 0; i < 8; ++i) {
    union { float f; uint32_t u; } a, h, d;
    a.f = x[i];
    const uint32_t hb = (a.u + 0x7fffu + ((a.u >> 16) & 1u)) >> 16;
    h.u = hb << 16;
    d.f = x[i] - h.f;
    const uint32_t lb = (d.u + 0x7fffu + ((d.u >> 16) & 1u)) >> 16;
    hi[i] = (short)hb;
    lo[i] = (short)lb;
  }
}

__device__ __forceinline__ void split1(float x, short* hs, short* ls)
{
  union { float f; uint32_t u; } a, h, d;
  a.f = x;
  const uint32_t hb = (a.u + 0x7fffu + ((a.u >> 16) & 1u)) >> 16;
  h.u = hb << 16;
  d.f = x - h.f;
  const uint32_t lb = (d.u + 0x7fffu + ((d.u >> 16) & 1u)) >> 16;
  *hs = (short)hb; *ls = (short)lb;
}

// async global -> LDS DMA, 16B per lane, dest = wave-uniform base + lane*16
__device__ __forceinline__ void gl_lds16(const void* g, void* l)
{
  __builtin_amdgcn_global_load_lds(
      (const __attribute__((address_space(1))) void*)g,
      (__attribute__((address_space(3))) void*)l, 16, 0, 0);
}

// ============================ compression (fused bf16 split outputs) ============================
// Same reduction as the known-good kernel; epilogue writes bf16 hi/lo directly:
//   kv==0 -> khi/klo [bh][256 n][128 d];  kv==1 -> vthi/vtlo [bh][128 d][256 n] (transposed).
// tile==63 blocks also zero the n=255 padding row/col (NaN-safety for 0*pad MFMA terms).
__global__ __launch_bounds__(256) void compress_kernel(
    const float* __restrict__ kin, const float* __restrict__ vin,
    const float* __restrict__ wk,  const float* __restrict__ wv,
    const float* __restrict__ pek, const float* __restrict__ pev,
    short* __restrict__ khi, short* __restrict__ klo,
    short* __restrict__ vthi, short* __restrict__ vtlo)
{
  __shared__ float xL[80 * 128];
  __shared__ float peL[4096];
  __shared__ float red[3 * 32 * 20];

  const int tid  = threadIdx.x;
  const int bid  = blockIdx.x;
  const int kv   = bid & 1;
  const int tile = (bid >> 1) & 63;
  const int bh   = bid >> 7;
  const int b = bh >> 1, h = bh & 1;

  const float* x  = kv ? vin : kin;
  const float* w  = kv ? wv  : wk;
  const float* pe = kv ? pev : pek;

  const float4* x4  = (const float4*)x;
  const float4* w4  = (const float4*)w;
  const float4* pe4 = (const float4*)pe;

  #pragma unroll
  for (int i = 0; i < 10; ++i) {
    const int f = tid + (i << 8);
    const int r = f >> 5, d4 = f & 31;
    long gr = (long)b * SEQ + tile * 64 + r;
    if (gr > (long)BSZ * SEQ - 1) gr = (long)BSZ * SEQ - 1;
    const float4 val = x4[(gr * HKVN + h) * 32 + d4];
    *(float4*)&xL[r * 128 + d4 * 4] = val;
  }
  #pragma unroll
  for (int i = 0; i < 4; ++i) {
    const int f = tid + (i << 8);
    *(float4*)&peL[f * 4] = pe4[f];
  }
  __syncthreads();

  const int dg = tid & 31, part = tid >> 5;
  float4 a0 = {0,0,0,0}, a1 = {0,0,0,0}, a2 = {0,0,0,0}, a3 = {0,0,0,0}, ab = {0,0,0,0};
  const int e0 = part * 512;
  #pragma unroll 4
  for (int it = 0; it < 512; ++it) {
    const int e = e0 + it;
    const float4 wv4 = w4[e * 32 + dg];
    const float pv = peL[e];
    const float x0 = xL[e], x1 = xL[2048 + e], x2 = xL[4096 + e], x3 = xL[6144 + e];
    ab.x += pv * wv4.x; ab.y += pv * wv4.y; ab.z += pv * wv4.z; ab.w += pv * wv4.w;
    a0.x += x0 * wv4.x; a0.y += x0 * wv4.y; a0.z += x0 * wv4.z; a0.w += x0 * wv4.w;
    a1.x += x1 * wv4.x; a1.y += x1 * wv4.y; a1.z += x1 * wv4.z; a1.w += x1 * wv4.w;
    a2.x += x2 * wv4.x; a2.y += x2 * wv4.y; a2.z += x2 * wv4.z; a2.w += x2 * wv4.w;
    a3.x += x3 * wv4.x; a3.y += x3 * wv4.y; a3.z += x3 * wv4.z; a3.w += x3 * wv4.w;
  }
  a0.x += __shfl_xor(a0.x, 32); a0.y += __shfl_xor(a0.y, 32); a0.z += __shfl_xor(a0.z, 32); a0.w += __shfl_xor(a0.w, 32);
  a1.x += __shfl_xor(a1.x, 32); a1.y += __shfl_xor(a1.y, 32); a1.z += __shfl_xor(a1.z, 32); a1.w += __shfl_xor(a1.w, 32);
  a2.x += __shfl_xor(a2.x, 32); a2.y += __shfl_xor(a2.y, 32); a2.z += __shfl_xor(a2.z, 32); a2.w += __shfl_xor(a2.w, 32);
  a3.x += __shfl_xor(a3.x, 32); a3.y += __shfl_xor(a3.y, 32); a3.z += __shfl_xor(a3.z, 32); a3.w += __shfl_xor(a3.w, 32);
  ab.x += __shfl_xor(ab.x, 32); ab.y += __shfl_xor(ab.y, 32); ab.z += __shfl_xor(ab.z, 32); ab.w += __shfl_xor(ab.w, 32);

  const int wv_ = tid >> 6, inw = tid & 63;
  if (wv_ > 0 && inw < 32) {
    float* rp = &red[((wv_ - 1) * 32 + dg) * 20];
    rp[0] = a0.x; rp[1] = a0.y; rp[2] = a0.z; rp[3] = a0.w;
    rp[4] = a1.x; rp[5] = a1.y; rp[6] = a1.z; rp[7] = a1.w;
    rp[8] = a2.x; rp[9] = a2.y; rp[10] = a2.z; rp[11] = a2.w;
    rp[12] = a3.x; rp[13] = a3.y; rp[14] = a3.z; rp[15] = a3.w;
    rp[16] = ab.x; rp[17] = ab.y; rp[18] = ab.z; rp[19] = ab.w;
  }
  __syncthreads();
  if (tid < 32) {
    #pragma unroll
    for (int wvv = 0; wvv < 3; ++wvv) {
      const float* rp = &red[(wvv * 32 + tid) * 20];
      a0.x += rp[0]; a0.y += rp[1]; a0.z += rp[2]; a0.w += rp[3];
      a1.x += rp[4]; a1.y += rp[5]; a1.z += rp[6]; a1.w += rp[7];
      a2.x += rp[8]; a2.y += rp[9]; a2.z += rp[10]; a2.w += rp[11];
      a3.x += rp[12]; a3.y += rp[13]; a3.z += rp[14]; a3.w += rp[15];
      ab.x += rp[16]; ab.y += rp[17]; ab.z += rp[18]; ab.w += rp[19];
    }
    const int n0 = tile * 4;
    const int bhn = b * HKVN + h;

    #define EMIT_ROW(I, AI) do {                                              \
      if (n0 + (I) < NBK) {                                                   \
        float xv[4] = { AI.x + ab.x, AI.y + ab.y, AI.z + ab.z, AI.w + ab.w }; \
        short hh[4], ll[4];                                                   \
        _Pragma("unroll")                                                     \
        for (int j = 0; j < 4; ++j) split1(xv[j], &hh[j], &ll[j]);            \
        if (kv == 0) {                                                        \
          const size_t base = ((size_t)(bhn * NBP + n0 + (I))) * DIM + tid * 4; \
          _Pragma("unroll")                                                   \
          for (int j = 0; j < 4; ++j) { khi[base + j] = hh[j]; klo[base + j] = ll[j]; } \
        } else {                                                              \
          _Pragma("unroll")                                                   \
          for (int j = 0; j < 4; ++j) {                                       \
            const size_t vb = ((size_t)(bhn * DIM) + tid * 4 + j) * NBP + n0 + (I); \
            vthi[vb] = hh[j]; vtlo[vb] = ll[j];                               \
          }                                                                   \
        }                                                                     \
      }                                                                       \
    } while (0)

    EMIT_ROW(0, a0);
    EMIT_ROW(1, a1);
    EMIT_ROW(2, a2);
    EMIT_ROW(3, a3);
    #undef EMIT_ROW
  }

  // zero the n=255 padding (row for kcb, col for vcT)
  if (tile == 63 && tid >= 64 && tid < 96) {
    const int t2 = tid - 64;
    const int bhn = b * HKVN + h;
    if (kv == 0) {
      const size_t base = ((size_t)(bhn * NBP + 255)) * DIM + t2 * 4;
      #pragma unroll
      for (int j = 0; j < 4; ++j) { khi[base + j] = 0; klo[base + j] = 0; }
    } else {
      #pragma unroll
      for (int j = 0; j < 4; ++j) {
        const size_t vb = ((size_t)(bhn * DIM) + t2 * 4 + j) * NBP + 255;
        vthi[vb] = 0; vtlo[vb] = 0;
      }
    }
  }
}

// ============================ fused attention (async-pipelined LDS, 8 waves) ============================
// grid 2048 = bh(4) x stile(512), block 512 = 8 waves. Wave w owns query s = s0+w.
// K phase: double-buffered global_load_lds DMA (issue cc+1 before MFMA cc; __syncthreads
// drain overlaps load flight with MFMA). V chunk 0 issued under the last K MFMA.
// LDS swizzle preserved by pre-swizzling the GLOBAL source (linear DMA dest).
__global__ __launch_bounds__(512, 4) void attn_kernel(
    const float* __restrict__ q,
    const short* __restrict__ khi, const short* __restrict__ klo,
    const short* __restrict__ vthi, const short* __restrict__ vtlo,
    float* __restrict__ outp, float* __restrict__ ap)
{
  __shared__ __align__(16) char smem[65536];

  const int tid  = threadIdx.x;
  const int bid  = blockIdx.x;
  const int stile = bid & 511;
  const int bh   = bid >> 9;
  const int b = bh >> 1, h = bh & 1;
  const int s0 = stile << 3;

  const int lane = tid & 63;
  const int w    = tid >> 6;
  const int l15  = lane & 15;
  const int l4   = lane >> 4;

  const int s    = s0 + w;
  const int nvis = (s >= 31) ? (((s - 31) >> 4) + 1) : 0;   // visible cols (wave-uniform)
  const int ntv  = (nvis + 15) >> 4;                        // visible 16-col tiles
  const int smax = s0 + 7;
  const int nvis_max = (smax >= 31) ? (((smax - 31) >> 4) + 1) : 0;
  const int nc  = (nvis_max + 63) >> 6;                     // block-uniform, 0..4

  // ---- Q A-frags straight from global (read once; scale folded; hi/lo split) ----
  bf16x8 qhi[4], qlo[4];
  {
    const float scale = 0.08838834764831845f;   // 1/sqrt(128)
    const float4* q4 = (const float4*)q;
    const size_t grow = (size_t)(b * SEQ + s) * HQN + h * GRP + l15;
    #pragma unroll
    for (int kk = 0; kk < 4; ++kk) {
      const float4 u  = q4[grow * 32 + kk * 8 + l4 * 2];
      const float4 u2 = q4[grow * 32 + kk * 8 + l4 * 2 + 1];
      float x[8];
      x[0] = u.x  * scale; x[1] = u.y  * scale; x[2] = u.z  * scale; x[3] = u.w  * scale;
      x[4] = u2.x * scale; x[5] = u2.y * scale; x[6] = u2.z * scale; x[7] = u2.w * scale;
      cvt8(x, qhi[kk], qlo[kk]);
    }
  }

  f32x4 acc1[16];
  #pragma unroll
  for (int nt = 0; nt < 16; ++nt) acc1[nt] = (f32x4)0.f;

  const short* kSrcH = khi + (size_t)bh * NBP * DIM;
  const short* kSrcL = klo + (size_t)bh * NBP * DIM;
  const short* vSrcH = vthi + (size_t)bh * DIM * NBP;
  const short* vSrcL = vtlo + (size_t)bh * DIM * NBP;

  // DMA granule plumbing: wave w issues granules f = (2w+i)*64 + lane, 16B each.
  // K dest granule (n, gs): value = khi[cc*64+n][ (gs^(n&15))*8 .. ]  (inverse-swizzled src)
  // V dest granule (d, gs): value = vt [d][ cc*64 + (gs^(d&7))*8 .. ]
  const int f0 = (((w << 1) | 0) << 6) | lane;
  const int f1 = (((w << 1) | 1) << 6) | lane;
  const int kn0 = f0 >> 4, kg0 = f0 & 15;
  const int kn1 = f1 >> 4, kg1 = f1 & 15;
  const int koff0 = kn0 * DIM + ((kg0 ^ (kn0 & 15)) << 3);
  const int koff1 = kn1 * DIM + ((kg1 ^ (kn1 & 15)) << 3);
  const int vd0 = f0 >> 3, vg0 = f0 & 7;
  const int vd1 = f1 >> 3, vg1 = f1 & 7;
  const int voff0 = vd0 * NBP + ((vg0 ^ (vd0 & 7)) << 3);
  const int voff1 = vd1 * NBP + ((vg1 ^ (vd1 & 7)) << 3);
  const int dst0 = (((w << 1) | 0) << 9);   // shorts (1 KB per wave-instr)
  const int dst1 = (((w << 1) | 1) << 9);

  #define KBUF_H(p) ((short*)(smem + ((p) ? 32768 : 0)))
  #define KBUF_L(p) (KBUF_H(p) + 8192)

  const int vhalf = nc & 1;                 // V region = K buffer NOT used by last K chunk
  short* sVhi = (short*)(smem + (vhalf ? 32768 : 0));
  short* sVlo = sVhi + 8192;
  float* smP  = (float*)(smem + (vhalf ? 0 : 32768));
  float* myP  = smP + (w << 10);            // this wave's 16x64 f32 region

  #define STAGE_K(CC, P) do {                                     \
    const size_t cb_ = (size_t)((CC) << 6) * DIM;                 \
    gl_lds16(kSrcH + cb_ + koff0, KBUF_H(P) + dst0);              \
    gl_lds16(kSrcH + cb_ + koff1, KBUF_H(P) + dst1);              \
    gl_lds16(kSrcL + cb_ + koff0, KBUF_L(P) + dst0);              \
    gl_lds16(kSrcL + cb_ + koff1, KBUF_L(P) + dst1);              \
  } while (0)

  #define STAGE_V(CC) do {                                        \
    const int cb_ = (CC) << 6;                                    \
    gl_lds16(vSrcH + cb_ + voff0, sVhi + dst0);                   \
    gl_lds16(vSrcH + cb_ + voff1, sVhi + dst1);                   \
    gl_lds16(vSrcL + cb_ + voff0, sVlo + dst0);                   \
    gl_lds16(vSrcL + cb_ + voff1, sVlo + dst1);                   \
  } while (0)

  // ---- GEMM1: scores = (scale*Q) @ kc^T, double-buffered async pipeline ----
  if (nc > 0) {
    STAGE_K(0, 0);
    __syncthreads();
    #pragma unroll
    for (int cc = 0; cc < 4; ++cc) {
      if (cc < nc) {                       // block-uniform
        if (cc + 1 < nc) { STAGE_K(cc + 1, (cc + 1) & 1); }
        else             { STAGE_V(0); }   // early V0 under last K MFMA
        __builtin_amdgcn_s_setprio(1);
        {
          const short* bH = KBUF_H(cc & 1);
          const short* bL = KBUF_L(cc & 1);
          const int base = cc << 2;
          if (ntv > base) {
            #pragma unroll
            for (int kk = 0; kk < 4; ++kk) {
              #pragma unroll
              for (int t = 0; t < 4; ++t) {
                if (base + t < ntv) {
                  const int n = (t << 4) | l15;
                  const int g = ((kk << 2) | l4) ^ l15;
                  const bf16x8 bHi = *(const bf16x8*)&bH[n * 128 + (g << 3)];
                  const bf16x8 bLo = *(const bf16x8*)&bL[n * 128 + (g << 3)];
                  acc1[base + t] = MFMA16(qhi[kk], bHi, acc1[base + t]);
                  acc1[base + t] = MFMA16(qlo[kk], bHi, acc1[base + t]);
                  acc1[base + t] = MFMA16(qhi[kk], bLo, acc1[base + t]);
                }
              }
            }
          }
        }
        __builtin_amdgcn_s_setprio(0);
        __syncthreads();                   // drains the in-flight DMA (overlapped with MFMA)
      }
    }
  }

  // ---- softmax in registers (rows: (l4<<2)+j; cols: nt*16 + l15) ----
  #pragma unroll
  for (int j = 0; j < 4; ++j) {
    float mv = -3.0e38f;
    #pragma unroll
    for (int nt = 0; nt < 16; ++nt) {
      const int col = (nt << 4) | l15;
      if (col < nvis) mv = fmaxf(mv, acc1[nt][j]);
    }
    mv = fmaxf(mv, __shfl_xor(mv, 1));
    mv = fmaxf(mv, __shfl_xor(mv, 2));
    mv = fmaxf(mv, __shfl_xor(mv, 4));
    mv = fmaxf(mv, __shfl_xor(mv, 8));
    float l = 0.f;
    #pragma unroll
    for (int nt = 0; nt < 16; ++nt) {
      const int col = (nt << 4) | l15;
      const float e = (col < nvis) ? __expf(acc1[nt][j] - mv) : 0.f;
      acc1[nt][j] = e;
      l += e;
    }
    l += __shfl_xor(l, 1); l += __shfl_xor(l, 2);
    l += __shfl_xor(l, 4); l += __shfl_xor(l, 8);
    const float inv = 1.f / fmaxf(l, 1e-20f);
    #pragma unroll
    for (int nt = 0; nt < 16; ++nt) acc1[nt][j] *= inv;
  }

  // ---- PV + ap stores; V single-buffered, issued early each iteration ----
  f32x4 acc2[8];
  #pragma unroll
  for (int dt = 0; dt < 8; ++dt) acc2[dt] = (f32x4)0.f;

  float* apB = ap + ((size_t)(b * HQN + h * GRP) * SEQ + s) * NBK;
  const size_t apStride = (size_t)SEQ * NBK;

  #pragma unroll
  for (int cc = 0; cc < 4; ++cc) {
    if (cc < nc) {                         // block-uniform
      // write this wave's 16 P rows (chunk-local cols), wave-private region
      #pragma unroll
      for (int tl = 0; tl < 4; ++tl) {
        #pragma unroll
        for (int j = 0; j < 4; ++j) {
          const int r = (l4 << 2) + j;
          const int c = (tl << 4) | l15;
          myP[r * 64 + ((((c >> 2) ^ ((r & 7) << 1)) << 2) | (c & 3))] = acc1[(cc << 2) + tl][j];
        }
      }
      __syncthreads();                     // drains V(cc) DMA + barrier
      // coalesced ap stores (includes causal zeros), streaming
      {
        const int c = (cc << 6) | lane;
        if (c < NBK) {
          #pragma unroll
          for (int kkr = 0; kkr < 16; ++kkr) {
            __builtin_nontemporal_store(
              myP[kkr * 64 + ((((lane >> 2) ^ ((kkr & 7) << 1)) << 2) | (lane & 3))],
              &apB[(size_t)kkr * apStride + c]);
          }
        }
      }
      // PV accumulate (wave-gated on visibility; trailing P cols are exact zeros)
      __builtin_amdgcn_s_setprio(1);
      {
        const int kbase = cc << 6;
        #pragma unroll
        for (int kl = 0; kl < 2; ++kl) {
          if (kbase + (kl << 5) < nvis) {
            const int c4s = ((kl << 3) | (l4 << 1)) ^ ((l15 & 7) << 1);
            float xp[8];
            *(float4*)&xp[0] = *(const float4*)&myP[l15 * 64 + (c4s << 2)];
            *(float4*)&xp[4] = *(const float4*)&myP[l15 * 64 + (c4s << 2) + 4];
            bf16x8 phi, plo;
            cvt8(xp, phi, plo);
            #pragma unroll
            for (int dt = 0; dt < 8; ++dt) {
              const int d = (dt << 4) | l15;
              const int g = ((kl << 2) | l4) ^ (l15 & 7);
              const bf16x8 vHi = *(const bf16x8*)&sVhi[d * 64 + (g << 3)];
              const bf16x8 vLo = *(const bf16x8*)&sVlo[d * 64 + (g << 3)];
              acc2[dt] = MFMA16(phi, vHi, acc2[dt]);
              acc2[dt] = MFMA16(plo, vHi, acc2[dt]);
              acc2[dt] = MFMA16(phi, vLo, acc2[dt]);
            }
          }
        }
      }
      __builtin_amdgcn_s_setprio(0);
      __syncthreads();                     // all waves done reading sV
      if (cc + 1 < nc) STAGE_V(cc + 1);    // fly under next P-writes/ap-stores
    }
  }

  // zero-fill attn_prob for fully-masked chunks
  for (int cc = nc; cc < 4; ++cc) {
    const int c = (cc << 6) | lane;
    if (c < NBK) {
      #pragma unroll
      for (int kkr = 0; kkr < 16; ++kkr)
        __builtin_nontemporal_store(0.f, &apB[(size_t)kkr * apStride + c]);
    }
  }

  // out stores (D-layout: row g=(l4<<2)+j, col d=dt*16+l15), streaming
  #pragma unroll
  for (int dt = 0; dt < 8; ++dt) {
    #pragma unroll
    for (int j = 0; j < 4; ++j) {
      const int g = (l4 << 2) + j;
      const size_t ob = ((size_t)(b * SEQ + s) * HQN + h * GRP + g) * DIM + (dt << 4) + l15;
      __builtin_nontemporal_store(acc2[dt][j], &outp[ob]);
    }
  }

  #undef STAGE_K
  #undef STAGE_V
  #undef KBUF_H
  #undef KBUF_L
}

extern "C" void kernel_launch(void* const* d_in, const int* in_sizes, int n_in,
                              void* d_out, int out_size, void* d_ws, size_t ws_size,
                              hipStream_t stream)
{
  const float* q   = (const float*)d_in[0];
  const float* k   = (const float*)d_in[1];
  const float* v   = (const float*)d_in[2];
  // d_in[3] cu_seqlens_k fixed [0,S,2S]; d_in[8] causal=True; d_in[9] scale=1/sqrt(128) hardcoded
  const float* wk  = (const float*)d_in[4];
  const float* wv  = (const float*)d_in[5];
  const float* pek = (const float*)d_in[6];
  const float* pev = (const float*)d_in[7];

  float* outp = (float*)d_out;
  float* ap   = outp + (size_t)BSZ * SEQ * HQN * DIM;

  const size_t sz = (size_t)BSZ * HKVN * NBP * DIM;   // 131072 shorts per array
  short* khi  = (short*)d_ws;                          // [bh][256][128] bf16 hi
  short* klo  = khi + sz;
  short* vthi = klo + sz;                              // [bh][128][256] bf16 hi (transposed)
  short* vtlo = vthi + sz;

  compress_kernel<<<dim3(512), dim3(256), 0, stream>>>(k, v, wk, wv, pek, pev, khi, klo, vthi, vtlo);
  attn_kernel<<<dim3(2048), dim3(512), 0, stream>>>(q, khi, klo, vthi, vtlo, outp, ap);
}

// Round 4
// 659.192 us; speedup vs baseline: 1.0919x; 1.0919x over previous
//
#include <hip/hip_runtime.h>
#include <cstddef>
#include <cstdint>

#define BSZ  2
#define SEQ  4096
#define HQN  32
#define HKVN 2
#define DIM  128
#define NBK  255
#define NBP  256
#define GRP  16

typedef __attribute__((ext_vector_type(8))) short bf16x8;
typedef __attribute__((ext_vector_type(4))) float f32x4;

#define MFMA16(A,B,C) __builtin_amdgcn_mfma_f32_16x16x32_bf16((A),(B),(C),0,0,0)

// split x into bf16 hi + bf16 lo (RNE both): x ~= hi + lo, |dropped| ~ 2^-18 |x|
__device__ __forceinline__ void cvt8(const float* x, bf16x8& hi, bf16x8& lo)
{
  #pragma unroll
  for (int i = 0; i < 8; ++i) {
    union { float f; uint32_t u; } a, h, d;
    a.f = x[i];
    const uint32_t hb = (a.u + 0x7fffu + ((a.u >> 16) & 1u)) >> 16;
    h.u = hb << 16;
    d.f = x[i] - h.f;
    const uint32_t lb = (d.u + 0x7fffu + ((d.u >> 16) & 1u)) >> 16;
    hi[i] = (short)hb;
    lo[i] = (short)lb;
  }
}

// async global -> LDS DMA, 16B per lane, dest = wave-uniform base + lane*16
__device__ __forceinline__ void gl_lds16(const void* g, void* l)
{
  __builtin_amdgcn_global_load_lds(
      (const __attribute__((address_space(1))) void*)g,
      (__attribute__((address_space(3))) void*)l, 16, 0, 0);
}

// ============================ compression (round-2 verified version) ============================
__global__ __launch_bounds__(256) void compress_kernel(
    const float* __restrict__ kin, const float* __restrict__ vin,
    const float* __restrict__ wk,  const float* __restrict__ wv,
    const float* __restrict__ pek, const float* __restrict__ pev,
    float* __restrict__ kc, float* __restrict__ vc)
{
  __shared__ float xL[80 * 128];
  __shared__ float peL[4096];
  __shared__ float red[3 * 32 * 20];

  const int tid  = threadIdx.x;
  const int bid  = blockIdx.x;
  const int kv   = bid & 1;
  const int tile = (bid >> 1) & 63;
  const int bh   = bid >> 7;
  const int b = bh >> 1, h = bh & 1;

  const float* x  = kv ? vin : kin;
  const float* w  = kv ? wv  : wk;
  const float* pe = kv ? pev : pek;
  float* outc     = kv ? vc  : kc;

  const float4* x4  = (const float4*)x;
  const float4* w4  = (const float4*)w;
  const float4* pe4 = (const float4*)pe;

  #pragma unroll
  for (int i = 0; i < 10; ++i) {
    const int f = tid + (i << 8);
    const int r = f >> 5, d4 = f & 31;
    long gr = (long)b * SEQ + tile * 64 + r;
    if (gr > (long)BSZ * SEQ - 1) gr = (long)BSZ * SEQ - 1;
    const float4 val = x4[(gr * HKVN + h) * 32 + d4];
    *(float4*)&xL[r * 128 + d4 * 4] = val;
  }
  #pragma unroll
  for (int i = 0; i < 4; ++i) {
    const int f = tid + (i << 8);
    *(float4*)&peL[f * 4] = pe4[f];
  }
  __syncthreads();

  const int dg = tid & 31, part = tid >> 5;
  float4 a0 = {0,0,0,0}, a1 = {0,0,0,0}, a2 = {0,0,0,0}, a3 = {0,0,0,0}, ab = {0,0,0,0};
  const int e0 = part * 512;
  #pragma unroll 4
  for (int it = 0; it < 512; ++it) {
    const int e = e0 + it;
    const float4 wv4 = w4[e * 32 + dg];
    const float pv = peL[e];
    const float x0 = xL[e], x1 = xL[2048 + e], x2 = xL[4096 + e], x3 = xL[6144 + e];
    ab.x += pv * wv4.x; ab.y += pv * wv4.y; ab.z += pv * wv4.z; ab.w += pv * wv4.w;
    a0.x += x0 * wv4.x; a0.y += x0 * wv4.y; a0.z += x0 * wv4.z; a0.w += x0 * wv4.w;
    a1.x += x1 * wv4.x; a1.y += x1 * wv4.y; a1.z += x1 * wv4.z; a1.w += x1 * wv4.w;
    a2.x += x2 * wv4.x; a2.y += x2 * wv4.y; a2.z += x2 * wv4.z; a2.w += x2 * wv4.w;
    a3.x += x3 * wv4.x; a3.y += x3 * wv4.y; a3.z += x3 * wv4.z; a3.w += x3 * wv4.w;
  }
  a0.x += __shfl_xor(a0.x, 32); a0.y += __shfl_xor(a0.y, 32); a0.z += __shfl_xor(a0.z, 32); a0.w += __shfl_xor(a0.w, 32);
  a1.x += __shfl_xor(a1.x, 32); a1.y += __shfl_xor(a1.y, 32); a1.z += __shfl_xor(a1.z, 32); a1.w += __shfl_xor(a1.w, 32);
  a2.x += __shfl_xor(a2.x, 32); a2.y += __shfl_xor(a2.y, 32); a2.z += __shfl_xor(a2.z, 32); a2.w += __shfl_xor(a2.w, 32);
  a3.x += __shfl_xor(a3.x, 32); a3.y += __shfl_xor(a3.y, 32); a3.z += __shfl_xor(a3.z, 32); a3.w += __shfl_xor(a3.w, 32);
  ab.x += __shfl_xor(ab.x, 32); ab.y += __shfl_xor(ab.y, 32); ab.z += __shfl_xor(ab.z, 32); ab.w += __shfl_xor(ab.w, 32);

  const int wv_ = tid >> 6, inw = tid & 63;
  if (wv_ > 0 && inw < 32) {
    float* rp = &red[((wv_ - 1) * 32 + dg) * 20];
    rp[0] = a0.x; rp[1] = a0.y; rp[2] = a0.z; rp[3] = a0.w;
    rp[4] = a1.x; rp[5] = a1.y; rp[6] = a1.z; rp[7] = a1.w;
    rp[8] = a2.x; rp[9] = a2.y; rp[10] = a2.z; rp[11] = a2.w;
    rp[12] = a3.x; rp[13] = a3.y; rp[14] = a3.z; rp[15] = a3.w;
    rp[16] = ab.x; rp[17] = ab.y; rp[18] = ab.z; rp[19] = ab.w;
  }
  __syncthreads();
  if (tid < 32) {
    #pragma unroll
    for (int wvv = 0; wvv < 3; ++wvv) {
      const float* rp = &red[(wvv * 32 + tid) * 20];
      a0.x += rp[0]; a0.y += rp[1]; a0.z += rp[2]; a0.w += rp[3];
      a1.x += rp[4]; a1.y += rp[5]; a1.z += rp[6]; a1.w += rp[7];
      a2.x += rp[8]; a2.y += rp[9]; a2.z += rp[10]; a2.w += rp[11];
      a3.x += rp[12]; a3.y += rp[13]; a3.z += rp[14]; a3.w += rp[15];
      ab.x += rp[16]; ab.y += rp[17]; ab.z += rp[18]; ab.w += rp[19];
    }
    const int n0 = tile * 4;
    float4 o;
    if (n0 + 0 < NBK) { o.x = a0.x + ab.x; o.y = a0.y + ab.y; o.z = a0.z + ab.z; o.w = a0.w + ab.w;
      *(float4*)&outc[((size_t)((b * HKVN + h) * NBK + n0 + 0)) * DIM + tid * 4] = o; }
    if (n0 + 1 < NBK) { o.x = a1.x + ab.x; o.y = a1.y + ab.y; o.z = a1.z + ab.z; o.w = a1.w + ab.w;
      *(float4*)&outc[((size_t)((b * HKVN + h) * NBK + n0 + 1)) * DIM + tid * 4] = o; }
    if (n0 + 2 < NBK) { o.x = a2.x + ab.x; o.y = a2.y + ab.y; o.z = a2.z + ab.z; o.w = a2.w + ab.w;
      *(float4*)&outc[((size_t)((b * HKVN + h) * NBK + n0 + 2)) * DIM + tid * 4] = o; }
    if (n0 + 3 < NBK) { o.x = a3.x + ab.x; o.y = a3.y + ab.y; o.z = a3.z + ab.z; o.w = a3.w + ab.w;
      *(float4*)&outc[((size_t)((b * HKVN + h) * NBK + n0 + 3)) * DIM + tid * 4] = o; }
  }
}

// ============================ bf16 hi/lo split + vc transpose (round-2 verified) ============================
__global__ __launch_bounds__(256) void convert_kernel(
    const float* __restrict__ kc, const float* __restrict__ vc,
    short* __restrict__ khi, short* __restrict__ klo,
    short* __restrict__ vthi, short* __restrict__ vtlo)
{
  const int T = blockIdx.x * 256 + threadIdx.x;
  float x[8];
  bf16x8 hi, lo;
  if (T < 16384) {
    const int bh = T >> 12, n = (T >> 4) & 255, d8 = T & 15;
    if (n < NBK) {
      const float4* p4 = (const float4*)(kc + ((size_t)bh * NBK + n) * DIM);
      const float4 u = p4[d8 * 2], v2 = p4[d8 * 2 + 1];
      x[0]=u.x; x[1]=u.y; x[2]=u.z; x[3]=u.w; x[4]=v2.x; x[5]=v2.y; x[6]=v2.z; x[7]=v2.w;
    } else {
      #pragma unroll
      for (int i = 0; i < 8; ++i) x[i] = 0.f;
    }
    cvt8(x, hi, lo);
    *(bf16x8*)(khi + ((size_t)bh * NBP + n) * DIM + d8 * 8) = hi;
    *(bf16x8*)(klo + ((size_t)bh * NBP + n) * DIM + d8 * 8) = lo;
  } else {
    const int T2 = T - 16384;
    const int bh = T2 >> 12, d = (T2 >> 5) & 127, n8 = T2 & 31;
    #pragma unroll
    for (int jj = 0; jj < 8; ++jj) {
      const int n = n8 * 8 + jj;
      x[jj] = (n < NBK) ? vc[((size_t)bh * NBK + n) * DIM + d] : 0.f;
    }
    cvt8(x, hi, lo);
    *(bf16x8*)(vthi + ((size_t)bh * DIM + d) * NBP + n8 * 8) = hi;
    *(bf16x8*)(vtlo + ((size_t)bh * DIM + d) * NBP + n8 * 8) = lo;
  }
}

// ============================ fused attention (async pipeline, reg-direct ap stores) ============================
// grid 2048 = bh(4) x stile(512), block 512 = 8 waves. Wave w owns query s = s0+w.
// K phase: double-buffered global_load_lds DMA (issue cc+1 before MFMA cc).
// PV phase: pT write (wave-private) -> barrier (V ready) -> PV MFMA -> barrier ->
//           issue V(cc+1) DMA -> ap stores straight from acc1 registers (overlap DMA flight).
__global__ __launch_bounds__(512, 4) void attn_kernel(
    const float* __restrict__ q,
    const short* __restrict__ khi, const short* __restrict__ klo,
    const short* __restrict__ vthi, const short* __restrict__ vtlo,
    float* __restrict__ outp, float* __restrict__ ap)
{
  __shared__ __align__(16) char smem[65536];

  const int tid  = threadIdx.x;
  const int bid  = blockIdx.x;
  const int stile = bid & 511;
  const int bh   = bid >> 9;
  const int b = bh >> 1, h = bh & 1;
  const int s0 = stile << 3;

  const int lane = tid & 63;
  const int w    = tid >> 6;
  const int l15  = lane & 15;
  const int l4   = lane >> 4;

  const int s    = s0 + w;
  const int nvis = (s >= 31) ? (((s - 31) >> 4) + 1) : 0;   // visible cols (wave-uniform)
  const int ntv  = (nvis + 15) >> 4;                        // visible 16-col tiles
  const int smax = s0 + 7;
  const int nvis_max = (smax >= 31) ? (((smax - 31) >> 4) + 1) : 0;
  const int nc  = (nvis_max + 63) >> 6;                     // block-uniform, 0..4

  const short* kSrcH = khi + (size_t)bh * NBP * DIM;
  const short* kSrcL = klo + (size_t)bh * NBP * DIM;
  const short* vSrcH = vthi + (size_t)bh * DIM * NBP;
  const short* vSrcL = vtlo + (size_t)bh * DIM * NBP;

  // DMA granule plumbing (16B granules, linear LDS dest, inverse-swizzled global src)
  const int f0 = (((w << 1) | 0) << 6) | lane;
  const int f1 = (((w << 1) | 1) << 6) | lane;
  const int kn0 = f0 >> 4, kg0 = f0 & 15;
  const int kn1 = f1 >> 4, kg1 = f1 & 15;
  const int koff0 = kn0 * DIM + ((kg0 ^ (kn0 & 15)) << 3);
  const int koff1 = kn1 * DIM + ((kg1 ^ (kn1 & 15)) << 3);
  const int vd0 = f0 >> 3, vg0 = f0 & 7;
  const int vd1 = f1 >> 3, vg1 = f1 & 7;
  const int voff0 = vd0 * NBP + ((vg0 ^ (vd0 & 7)) << 3);
  const int voff1 = vd1 * NBP + ((vg1 ^ (vd1 & 7)) << 3);
  const int dst0 = (((w << 1) | 0) << 9);   // shorts
  const int dst1 = (((w << 1) | 1) << 9);

  #define KBUF_H(p) ((short*)(smem + ((p) ? 32768 : 0)))
  #define KBUF_L(p) (KBUF_H(p) + 8192)

  const int vhalf = nc & 1;                 // V region = K buffer NOT used by last K chunk
  short* sVhi = (short*)(smem + (vhalf ? 32768 : 0));
  short* sVlo = sVhi + 8192;
  float* smP  = (float*)(smem + (vhalf ? 0 : 32768));
  float* myP  = smP + (w << 10);            // this wave's 16x64 f32 region

  #define STAGE_K(CC, P) do {                                     \
    const size_t cb_ = (size_t)((CC) << 6) * DIM;                 \
    gl_lds16(kSrcH + cb_ + koff0, KBUF_H(P) + dst0);              \
    gl_lds16(kSrcH + cb_ + koff1, KBUF_H(P) + dst1);              \
    gl_lds16(kSrcL + cb_ + koff0, KBUF_L(P) + dst0);              \
    gl_lds16(kSrcL + cb_ + koff1, KBUF_L(P) + dst1);              \
  } while (0)

  #define STAGE_V(CC) do {                                        \
    const int cb_ = (CC) << 6;                                    \
    gl_lds16(vSrcH + cb_ + voff0, sVhi + dst0);                   \
    gl_lds16(vSrcH + cb_ + voff1, sVhi + dst1);                   \
    gl_lds16(vSrcL + cb_ + voff0, sVlo + dst0);                   \
    gl_lds16(vSrcL + cb_ + voff1, sVlo + dst1);                   \
  } while (0)

  // issue K chunk 0 DMA first: it flies under the Q load + cvt below
  if (nc > 0) STAGE_K(0, 0);

  // ---- Q A-frags straight from global (read once; scale folded; hi/lo split) ----
  bf16x8 qhi[4], qlo[4];
  {
    const float scale = 0.08838834764831845f;   // 1/sqrt(128)
    const float4* q4 = (const float4*)q;
    const size_t grow = (size_t)(b * SEQ + s) * HQN + h * GRP + l15;
    #pragma unroll
    for (int kk = 0; kk < 4; ++kk) {
      const float4 u  = q4[grow * 32 + kk * 8 + l4 * 2];
      const float4 u2 = q4[grow * 32 + kk * 8 + l4 * 2 + 1];
      float x[8];
      x[0] = u.x  * scale; x[1] = u.y  * scale; x[2] = u.z  * scale; x[3] = u.w  * scale;
      x[4] = u2.x * scale; x[5] = u2.y * scale; x[6] = u2.z * scale; x[7] = u2.w * scale;
      cvt8(x, qhi[kk], qlo[kk]);
    }
  }

  f32x4 acc1[16];
  #pragma unroll
  for (int nt = 0; nt < 16; ++nt) acc1[nt] = (f32x4)0.f;

  // ---- GEMM1: scores = (scale*Q) @ kc^T, double-buffered async pipeline ----
  if (nc > 0) {
    __syncthreads();
    #pragma unroll
    for (int cc = 0; cc < 4; ++cc) {
      if (cc < nc) {                       // block-uniform
        if (cc + 1 < nc) { STAGE_K(cc + 1, (cc + 1) & 1); }
        else             { STAGE_V(0); }   // early V0 under last K MFMA
        __builtin_amdgcn_s_setprio(1);
        {
          const short* bH = KBUF_H(cc & 1);
          const short* bL = KBUF_L(cc & 1);
          const int base = cc << 2;
          if (ntv > base) {
            #pragma unroll
            for (int kk = 0; kk < 4; ++kk) {
              #pragma unroll
              for (int t = 0; t < 4; ++t) {
                if (base + t < ntv) {
                  const int n = (t << 4) | l15;
                  const int g = ((kk << 2) | l4) ^ l15;
                  const bf16x8 bHi = *(const bf16x8*)&bH[n * 128 + (g << 3)];
                  const bf16x8 bLo = *(const bf16x8*)&bL[n * 128 + (g << 3)];
                  acc1[base + t] = MFMA16(qhi[kk], bHi, acc1[base + t]);
                  acc1[base + t] = MFMA16(qlo[kk], bHi, acc1[base + t]);
                  acc1[base + t] = MFMA16(qhi[kk], bLo, acc1[base + t]);
                }
              }
            }
          }
        }
        __builtin_amdgcn_s_setprio(0);
        __syncthreads();                   // drains in-flight DMA (overlapped with MFMA)
      }
    }
  }

  // ---- softmax in registers (rows: (l4<<2)+j; cols: nt*16 + l15) ----
  #pragma unroll
  for (int j = 0; j < 4; ++j) {
    float mv = -3.0e38f;
    #pragma unroll
    for (int nt = 0; nt < 16; ++nt) {
      const int col = (nt << 4) | l15;
      if (col < nvis) mv = fmaxf(mv, acc1[nt][j]);
    }
    mv = fmaxf(mv, __shfl_xor(mv, 1));
    mv = fmaxf(mv, __shfl_xor(mv, 2));
    mv = fmaxf(mv, __shfl_xor(mv, 4));
    mv = fmaxf(mv, __shfl_xor(mv, 8));
    float l = 0.f;
    #pragma unroll
    for (int nt = 0; nt < 16; ++nt) {
      const int col = (nt << 4) | l15;
      const float e = (col < nvis) ? __expf(acc1[nt][j] - mv) : 0.f;
      acc1[nt][j] = e;
      l += e;
    }
    l += __shfl_xor(l, 1); l += __shfl_xor(l, 2);
    l += __shfl_xor(l, 4); l += __shfl_xor(l, 8);
    const float inv = 1.f / fmaxf(l, 1e-20f);
    #pragma unroll
    for (int nt = 0; nt < 16; ++nt) acc1[nt][j] *= inv;
  }

  // ---- PV + ap stores ----
  f32x4 acc2[8];
  #pragma unroll
  for (int dt = 0; dt < 8; ++dt) acc2[dt] = (f32x4)0.f;

  float* apR = ap + ((size_t)(b * HQN + h * GRP) * SEQ + s) * NBK;  // + g*(SEQ*NBK) + c
  const size_t apStride = (size_t)SEQ * NBK;

  #pragma unroll
  for (int cc = 0; cc < 4; ++cc) {
    if (cc < nc) {                         // block-uniform
      // pT write (wave-private rows; no barrier needed for same-wave read)
      #pragma unroll
      for (int tl = 0; tl < 4; ++tl) {
        #pragma unroll
        for (int j = 0; j < 4; ++j) {
          const int r = (l4 << 2) + j;
          const int c = (tl << 4) | l15;
          myP[r * 64 + ((((c >> 2) ^ ((r & 7) << 1)) << 2) | (c & 3))] = acc1[(cc << 2) + tl][j];
        }
      }
      __syncthreads();                     // V(cc) DMA drained; all waves aligned
      // PV accumulate (wave-gated on visibility; trailing P cols are exact zeros)
      __builtin_amdgcn_s_setprio(1);
      {
        const int kbase = cc << 6;
        #pragma unroll
        for (int kl = 0; kl < 2; ++kl) {
          if (kbase + (kl << 5) < nvis) {
            const int c4s = ((kl << 3) | (l4 << 1)) ^ ((l15 & 7) << 1);
            float xp[8];
            *(float4*)&xp[0] = *(const float4*)&myP[l15 * 64 + (c4s << 2)];
            *(float4*)&xp[4] = *(const float4*)&myP[l15 * 64 + (c4s << 2) + 4];
            bf16x8 phi, plo;
            cvt8(xp, phi, plo);
            #pragma unroll
            for (int dt = 0; dt < 8; ++dt) {
              const int d = (dt << 4) | l15;
              const int g = ((kl << 2) | l4) ^ (l15 & 7);
              const bf16x8 vHi = *(const bf16x8*)&sVhi[d * 64 + (g << 3)];
              const bf16x8 vLo = *(const bf16x8*)&sVlo[d * 64 + (g << 3)];
              acc2[dt] = MFMA16(phi, vHi, acc2[dt]);
              acc2[dt] = MFMA16(plo, vHi, acc2[dt]);
              acc2[dt] = MFMA16(phi, vLo, acc2[dt]);
            }
          }
        }
      }
      __builtin_amdgcn_s_setprio(0);
      __syncthreads();                     // all waves done reading sV
      if (cc + 1 < nc) STAGE_V(cc + 1);    // DMA flies under ap stores + next pT writes
      // ap stores straight from registers (coalesced 4x64B segments per instr)
      #pragma unroll
      for (int tl = 0; tl < 4; ++tl) {
        const int c = (((cc << 2) + tl) << 4) | l15;
        if (c < NBK) {
          #pragma unroll
          for (int j = 0; j < 4; ++j) {
            const int g = (l4 << 2) + j;
            apR[(size_t)g * apStride + c] = acc1[(cc << 2) + tl][j];
          }
        }
      }
    }
  }

  // zero-fill attn_prob for fully-masked chunks (from registers)
  for (int cc = nc; cc < 4; ++cc) {
    #pragma unroll
    for (int tl = 0; tl < 4; ++tl) {
      const int c = (((cc << 2) + tl) << 4) | l15;
      if (c < NBK) {
        #pragma unroll
        for (int j = 0; j < 4; ++j) {
          const int g = (l4 << 2) + j;
          apR[(size_t)g * apStride + c] = 0.f;
        }
      }
    }
  }

  // out stores (D-layout: row g=(l4<<2)+j, col d=dt*16+l15); aligned 64B segments -> nt ok
  #pragma unroll
  for (int dt = 0; dt < 8; ++dt) {
    #pragma unroll
    for (int j = 0; j < 4; ++j) {
      const int g = (l4 << 2) + j;
      const size_t ob = ((size_t)(b * SEQ + s) * HQN + h * GRP + g) * DIM + (dt << 4) + l15;
      __builtin_nontemporal_store(acc2[dt][j], &outp[ob]);
    }
  }

  #undef STAGE_K
  #undef STAGE_V
  #undef KBUF_H
  #undef KBUF_L
}

extern "C" void kernel_launch(void* const* d_in, const int* in_sizes, int n_in,
                              void* d_out, int out_size, void* d_ws, size_t ws_size,
                              hipStream_t stream)
{
  const float* q   = (const float*)d_in[0];
  const float* k   = (const float*)d_in[1];
  const float* v   = (const float*)d_in[2];
  // d_in[3] cu_seqlens_k fixed [0,S,2S]; d_in[8] causal=True; d_in[9] scale=1/sqrt(128) hardcoded
  const float* wk  = (const float*)d_in[4];
  const float* wv  = (const float*)d_in[5];
  const float* pek = (const float*)d_in[6];
  const float* pev = (const float*)d_in[7];

  float* outp = (float*)d_out;
  float* ap   = outp + (size_t)BSZ * SEQ * HQN * DIM;

  float* kc   = (float*)d_ws;                                  // [bh][255][128] f32
  float* vc   = kc + (size_t)BSZ * HKVN * NBK * DIM;
  short* khi  = (short*)(vc + (size_t)BSZ * HKVN * NBK * DIM); // [bh][256][128] bf16 hi
  short* klo  = khi + (size_t)BSZ * HKVN * NBP * DIM;
  short* vthi = klo + (size_t)BSZ * HKVN * NBP * DIM;          // [bh][128][256] bf16 hi (transposed)
  short* vtlo = vthi + (size_t)BSZ * HKVN * NBP * DIM;

  compress_kernel<<<dim3(512), dim3(256), 0, stream>>>(k, v, wk, wv, pek, pev, kc, vc);
  convert_kernel<<<dim3(128), dim3(256), 0, stream>>>(kc, vc, khi, klo, vthi, vtlo);
  attn_kernel<<<dim3(2048), dim3(512), 0, stream>>>(q, khi, klo, vthi, vtlo, outp, ap);
}